// Round 2
// baseline (12931.973 us; speedup 1.0000x reference)
//
#include <hip/hip_runtime.h>
#include <cmath>

#define HID   512
#define VOCAB 100
#define G3    1536          // 3*HID
#define GEXT  1664          // G3 + 100 logits + pad
#define TMAX  201
#define ROWS  8
#define BLOCK 640
#define NWG   256

// ---- workspace layout (float offsets) ----
#define SZ_GTI   (HID * GEXT)          // 851968: interleaved [kc][j][kk4]
#define OFF_GTI  0
#define SZ_EIH   (VOCAB * G3)          // 153600: E_ih = embed @ W_ih^T + b_ih
#define OFF_EIH  (OFF_GTI + SZ_GTI)
#define SZ_WIHT  (HID * G3)            // 786432: W_ih transposed [k][j]
#define OFF_WIHT (OFF_EIH + SZ_EIH)
#define SZ_BEXT  GEXT                  // 1664: [b_hh | b_proj | 0-pad]
#define OFF_BEXT (OFF_WIHT + SZ_WIHT)
// total = 1,793,664 floats = ~7.2 MB of d_ws

// Build GTI (k4-interleaved extended weight matrix), W_ihT, bias_ext.
// GTI float index = (kc*GEXT + j)*4 + kk, where k = kc*4+kk.
// Columns j: [0,1536) = W_hh rows (r,z,n gates); [1536,1636) = W_proj rows; pad=0.
__global__ void prep_kernel(const float* __restrict__ W_ih,
                            const float* __restrict__ W_hh,
                            const float* __restrict__ b_hh,
                            const float* __restrict__ W_proj,
                            const float* __restrict__ b_proj,
                            float* __restrict__ ws)
{
  int idx = blockIdx.x * blockDim.x + threadIdx.x;
  const int total = SZ_GTI + SZ_WIHT + SZ_BEXT;
  if (idx >= total) return;
  if (idx < SZ_GTI) {
    int kc  = idx / (GEXT * 4);
    int rem = idx - kc * (GEXT * 4);
    int j   = rem >> 2;
    int kk  = rem & 3;
    int k   = kc * 4 + kk;
    float val = 0.f;
    if (j < G3)              val = W_hh[j * HID + k];
    else if (j < G3 + VOCAB) val = W_proj[(j - G3) * HID + k];
    ws[OFF_GTI + idx] = val;
  } else if (idx < SZ_GTI + SZ_WIHT) {
    int e = idx - SZ_GTI;
    int k = e / G3;
    int j = e - k * G3;
    ws[OFF_WIHT + e] = W_ih[j * HID + k];
  } else {
    int j = idx - SZ_GTI - SZ_WIHT;
    float val = 0.f;
    if (j < G3)              val = b_hh[j];
    else if (j < G3 + VOCAB) val = b_proj[j - G3];
    ws[OFF_BEXT + j] = val;
  }
}

// E_ih[v][j] = b_ih[j] + sum_k embed[v][k] * W_ih[j][k]   (coalesced via W_ihT)
__global__ void eih_kernel(const float* __restrict__ embed,
                           const float* __restrict__ b_ih,
                           float* __restrict__ ws)
{
  int v = blockIdx.x / 6;
  int j = (blockIdx.x % 6) * 256 + threadIdx.x;
  const float* WihT = ws + OFF_WIHT;
  const float* e = embed + v * HID;
  float acc = b_ih[j];
  for (int k = 0; k < HID; ++k)
    acc = fmaf(WihT[k * G3 + j], e[k], acc);
  ws[OFF_EIH + v * G3 + j] = acc;
}

// Persistent per-block GRU decode: 8 batch rows per block, 202 iterations.
// Iteration t: extended GEMV on h(=H_t) gives gh_t (cols 0..1535) and
// logits_{t-1} (cols 1536..1635); argmax -> pred_{t-1}; gate math -> H_{t+1}.
__global__ __launch_bounds__(BLOCK) void decode_kernel(
    const float* __restrict__ feat,
    const int* __restrict__ sos,
    const float* __restrict__ ws,
    float* __restrict__ out)
{
  __shared__ float h_lds[ROWS][HID];
  __shared__ float logits_lds[ROWS][132];   // stride 132 breaks argmax bank aliasing
  __shared__ int   pred_lds[ROWS];

  const float* __restrict__ GTI  = ws + OFF_GTI;
  const float* __restrict__ EIH  = ws + OFF_EIH;
  const float* __restrict__ bext = ws + OFF_BEXT;

  const int tid = threadIdx.x;
  const int b0  = blockIdx.x * ROWS;

  for (int i = tid; i < ROWS * HID; i += BLOCK) {
    int r = i >> 9, k = i & (HID - 1);
    h_lds[r][k] = feat[(b0 + r) * HID + k];
  }
  if (tid < ROWS) pred_lds[tid] = sos[0];
  __syncthreads();

  const bool is_gate = (tid < HID);   // threads [0,512): own unit u = tid (r,z,n triplet)
  const int  u = tid;
  const int  v = tid - HID;           // threads [512,640): logit column v in [0,128)

  float bias0 = 0.f, bias1 = 0.f, bias2 = 0.f;
  if (is_gate) { bias0 = bext[u]; bias1 = bext[HID + u]; bias2 = bext[2 * HID + u]; }
  else         { bias0 = bext[G3 + v]; }

  float accr[ROWS], accz[ROWS], accn[ROWS];

  for (int t = 0; t <= TMAX; ++t) {
    // ---------- phase A: extended GEMV over k ----------
    if (is_gate) {
      #pragma unroll
      for (int r = 0; r < ROWS; ++r) { accr[r] = bias0; accz[r] = bias1; accn[r] = bias2; }
      if (t < TMAX) {  // last iteration needs only logits
        const float4* pr = (const float4*)GTI + u;
        const float4* pz = (const float4*)GTI + HID + u;
        const float4* pn = (const float4*)GTI + 2 * HID + u;
        for (int kc = 0; kc < HID / 4; ++kc) {
          float4 wr = pr[kc * GEXT];
          float4 wz = pz[kc * GEXT];
          float4 wn = pn[kc * GEXT];
          #pragma unroll
          for (int r = 0; r < ROWS; ++r) {
            float4 hv = *(const float4*)&h_lds[r][kc * 4];   // LDS broadcast
            accr[r] = fmaf(wr.x, hv.x, accr[r]); accr[r] = fmaf(wr.y, hv.y, accr[r]);
            accr[r] = fmaf(wr.z, hv.z, accr[r]); accr[r] = fmaf(wr.w, hv.w, accr[r]);
            accz[r] = fmaf(wz.x, hv.x, accz[r]); accz[r] = fmaf(wz.y, hv.y, accz[r]);
            accz[r] = fmaf(wz.z, hv.z, accz[r]); accz[r] = fmaf(wz.w, hv.w, accz[r]);
            accn[r] = fmaf(wn.x, hv.x, accn[r]); accn[r] = fmaf(wn.y, hv.y, accn[r]);
            accn[r] = fmaf(wn.z, hv.z, accn[r]); accn[r] = fmaf(wn.w, hv.w, accn[r]);
          }
        }
      }
    } else {
      #pragma unroll
      for (int r = 0; r < ROWS; ++r) accr[r] = bias0;
      const float4* pv = (const float4*)GTI + G3 + v;
      for (int kc = 0; kc < HID / 4; ++kc) {
        float4 wv = pv[kc * GEXT];
        #pragma unroll
        for (int r = 0; r < ROWS; ++r) {
          float4 hv = *(const float4*)&h_lds[r][kc * 4];
          accr[r] = fmaf(wv.x, hv.x, accr[r]); accr[r] = fmaf(wv.y, hv.y, accr[r]);
          accr[r] = fmaf(wv.z, hv.z, accr[r]); accr[r] = fmaf(wv.w, hv.w, accr[r]);
        }
      }
      #pragma unroll
      for (int r = 0; r < ROWS; ++r) logits_lds[r][v] = accr[r];
      if (t >= 1 && v < VOCAB) {   // logits_{t-1} -> out[b][v][t-1]
        #pragma unroll
        for (int r = 0; r < ROWS; ++r)
          __builtin_nontemporal_store(
              accr[r], &out[((size_t)(b0 + r) * VOCAB + v) * TMAX + (t - 1)]);
      }
    }
    __syncthreads();

    // ---------- argmax (first-max, matches jnp.argmax) ----------
    if (t >= 1 && t < TMAX && tid < ROWS) {
      float best = logits_lds[tid][0];
      int bi = 0;
      for (int x = 1; x < VOCAB; ++x) {
        float val = logits_lds[tid][x];
        if (val > best) { best = val; bi = x; }
      }
      pred_lds[tid] = bi;
    }
    __syncthreads();

    // ---------- gate nonlinearity + h update (no gh LDS round-trip) ----------
    if (is_gate && t < TMAX) {
      #pragma unroll
      for (int r = 0; r < ROWS; ++r) {
        const float* eb = EIH + (size_t)pred_lds[r] * G3;
        float gir = eb[u], giz = eb[HID + u], gin = eb[2 * HID + u];
        float rg = 1.f / (1.f + expf(-(gir + accr[r])));
        float zg = 1.f / (1.f + expf(-(giz + accz[r])));
        float ng = tanhf(gin + rg * accn[r]);
        h_lds[r][u] = (1.f - zg) * ng + zg * h_lds[r][u];
      }
    }
    __syncthreads();
  }
}

extern "C" void kernel_launch(void* const* d_in, const int* in_sizes, int n_in,
                              void* d_out, int out_size, void* d_ws, size_t ws_size,
                              hipStream_t stream)
{
  const float* feat   = (const float*)d_in[0];
  const float* W_ih   = (const float*)d_in[1];
  const float* W_hh   = (const float*)d_in[2];
  const float* b_ih   = (const float*)d_in[3];
  const float* b_hh   = (const float*)d_in[4];
  const float* W_proj = (const float*)d_in[5];
  const float* b_proj = (const float*)d_in[6];
  const float* embed  = (const float*)d_in[7];
  const int*   sos    = (const int*)d_in[8];
  float* ws  = (float*)d_ws;
  float* out = (float*)d_out;

  const int total = SZ_GTI + SZ_WIHT + SZ_BEXT;
  prep_kernel<<<(total + 255) / 256, 256, 0, stream>>>(W_ih, W_hh, b_hh, W_proj, b_proj, ws);
  eih_kernel<<<600, 256, 0, stream>>>(embed, b_ih, ws);
  decode_kernel<<<NWG, BLOCK, 0, stream>>>(feat, sos, ws, out);
}

// Round 3
// 12915.399 us; speedup vs baseline: 1.0013x; 1.0013x over previous
//
#include <hip/hip_runtime.h>
#include <cmath>

#define HID   512
#define VOCAB 100
#define G3    1536          // 3*HID
#define GEXT  1664          // G3 + 100 logits + pad
#define TMAX  201
#define ROWS  8
#define BLOCK 640
#define NWG   256

// ---- workspace layout (float offsets) ----
#define SZ_GTI   (HID * GEXT)          // 851968: interleaved [kc][j][kk4]
#define OFF_GTI  0
#define SZ_EIH   (VOCAB * G3)          // 153600: E_ih = embed @ W_ih^T + b_ih
#define OFF_EIH  (OFF_GTI + SZ_GTI)
#define SZ_WIHT  (HID * G3)            // 786432: W_ih transposed [k][j]
#define OFF_WIHT (OFF_EIH + SZ_EIH)
#define SZ_BEXT  GEXT                  // 1664: [b_hh | b_proj | 0-pad]
#define OFF_BEXT (OFF_WIHT + SZ_WIHT)
// total = 1,793,664 floats = ~7.2 MB of d_ws

// Build GTI (k4-interleaved extended weight matrix), W_ihT, bias_ext.
// GTI float index = (kc*GEXT + j)*4 + kk, where k = kc*4+kk.
// Columns j: [0,1536) = W_hh rows (r,z,n gates); [1536,1636) = W_proj rows; pad=0.
__global__ void prep_kernel(const float* __restrict__ W_ih,
                            const float* __restrict__ W_hh,
                            const float* __restrict__ b_hh,
                            const float* __restrict__ W_proj,
                            const float* __restrict__ b_proj,
                            float* __restrict__ ws)
{
  int idx = blockIdx.x * blockDim.x + threadIdx.x;
  const int total = SZ_GTI + SZ_WIHT + SZ_BEXT;
  if (idx >= total) return;
  if (idx < SZ_GTI) {
    int kc  = idx / (GEXT * 4);
    int rem = idx - kc * (GEXT * 4);
    int j   = rem >> 2;
    int kk  = rem & 3;
    int k   = kc * 4 + kk;
    float val = 0.f;
    if (j < G3)              val = W_hh[j * HID + k];
    else if (j < G3 + VOCAB) val = W_proj[(j - G3) * HID + k];
    ws[OFF_GTI + idx] = val;
  } else if (idx < SZ_GTI + SZ_WIHT) {
    int e = idx - SZ_GTI;
    int k = e / G3;
    int j = e - k * G3;
    ws[OFF_WIHT + e] = W_ih[j * HID + k];
  } else {
    int j = idx - SZ_GTI - SZ_WIHT;
    float val = 0.f;
    if (j < G3)              val = b_hh[j];
    else if (j < G3 + VOCAB) val = b_proj[j - G3];
    ws[OFF_BEXT + j] = val;
  }
}

// E_ih[v][j] = b_ih[j] + sum_k embed[v][k] * W_ih[j][k]   (coalesced via W_ihT)
__global__ void eih_kernel(const float* __restrict__ embed,
                           const float* __restrict__ b_ih,
                           float* __restrict__ ws)
{
  int v = blockIdx.x / 6;
  int j = (blockIdx.x % 6) * 256 + threadIdx.x;
  const float* WihT = ws + OFF_WIHT;
  const float* e = embed + v * HID;
  float acc = b_ih[j];
  for (int k = 0; k < HID; ++k)
    acc = fmaf(WihT[k * G3 + j], e[k], acc);
  ws[OFF_EIH + v * G3 + j] = acc;
}

// Persistent per-block GRU decode: 8 batch rows per block, 202 iterations.
// Iteration t: extended GEMV on h(=H_t) gives gh_t (cols 0..1535) and
// logits_{t-1} (cols 1536..1635); argmax -> pred_{t-1}; gate math -> H_{t+1}.
__global__ __launch_bounds__(BLOCK) void decode_kernel(
    const float* __restrict__ feat,
    const int* __restrict__ sos,
    const float* __restrict__ ws,
    float* __restrict__ out)
{
  __shared__ float h_lds[ROWS][HID];
  __shared__ float logits_lds[ROWS][132];   // stride 132 breaks argmax bank aliasing
  __shared__ int   pred_lds[ROWS];

  const float* __restrict__ GTI  = ws + OFF_GTI;
  const float* __restrict__ EIH  = ws + OFF_EIH;
  const float* __restrict__ bext = ws + OFF_BEXT;

  const int tid = threadIdx.x;
  const int b0  = blockIdx.x * ROWS;

  for (int i = tid; i < ROWS * HID; i += BLOCK) {
    int r = i >> 9, k = i & (HID - 1);
    h_lds[r][k] = feat[(b0 + r) * HID + k];
  }
  if (tid < ROWS) pred_lds[tid] = sos[0];
  __syncthreads();

  const bool is_gate = (tid < HID);   // threads [0,512): own unit u = tid (r,z,n triplet)
  const int  u = tid;
  const int  v = tid - HID;           // threads [512,640): logit column v in [0,128)

  float bias0 = 0.f, bias1 = 0.f, bias2 = 0.f;
  if (is_gate) { bias0 = bext[u]; bias1 = bext[HID + u]; bias2 = bext[2 * HID + u]; }
  else         { bias0 = bext[G3 + v]; }

  float accr[ROWS], accz[ROWS], accn[ROWS];

  for (int t = 0; t <= TMAX; ++t) {
    // ---------- phase A: extended GEMV over k ----------
    if (is_gate) {
      #pragma unroll
      for (int r = 0; r < ROWS; ++r) { accr[r] = bias0; accz[r] = bias1; accn[r] = bias2; }
      if (t < TMAX) {  // last iteration needs only logits
        const float4* pr = (const float4*)GTI + u;
        const float4* pz = (const float4*)GTI + HID + u;
        const float4* pn = (const float4*)GTI + 2 * HID + u;
        for (int kc = 0; kc < HID / 4; ++kc) {
          float4 wr = pr[kc * GEXT];
          float4 wz = pz[kc * GEXT];
          float4 wn = pn[kc * GEXT];
          #pragma unroll
          for (int r = 0; r < ROWS; ++r) {
            float4 hv = *(const float4*)&h_lds[r][kc * 4];   // LDS broadcast
            accr[r] = fmaf(wr.x, hv.x, accr[r]); accr[r] = fmaf(wr.y, hv.y, accr[r]);
            accr[r] = fmaf(wr.z, hv.z, accr[r]); accr[r] = fmaf(wr.w, hv.w, accr[r]);
            accz[r] = fmaf(wz.x, hv.x, accz[r]); accz[r] = fmaf(wz.y, hv.y, accz[r]);
            accz[r] = fmaf(wz.z, hv.z, accz[r]); accz[r] = fmaf(wz.w, hv.w, accz[r]);
            accn[r] = fmaf(wn.x, hv.x, accn[r]); accn[r] = fmaf(wn.y, hv.y, accn[r]);
            accn[r] = fmaf(wn.z, hv.z, accn[r]); accn[r] = fmaf(wn.w, hv.w, accn[r]);
          }
        }
      }
    } else {
      #pragma unroll
      for (int r = 0; r < ROWS; ++r) accr[r] = bias0;
      const float4* pv = (const float4*)GTI + G3 + v;
      for (int kc = 0; kc < HID / 4; ++kc) {
        float4 wv = pv[kc * GEXT];
        #pragma unroll
        for (int r = 0; r < ROWS; ++r) {
          float4 hv = *(const float4*)&h_lds[r][kc * 4];
          accr[r] = fmaf(wv.x, hv.x, accr[r]); accr[r] = fmaf(wv.y, hv.y, accr[r]);
          accr[r] = fmaf(wv.z, hv.z, accr[r]); accr[r] = fmaf(wv.w, hv.w, accr[r]);
        }
      }
      #pragma unroll
      for (int r = 0; r < ROWS; ++r) logits_lds[r][v] = accr[r];
      if (t >= 1 && v < VOCAB) {   // logits_{t-1} -> out[b][v][t-1]
        #pragma unroll
        for (int r = 0; r < ROWS; ++r)
          __builtin_nontemporal_store(
              accr[r], &out[((size_t)(b0 + r) * VOCAB + v) * TMAX + (t - 1)]);
      }
    }
    __syncthreads();

    // ---------- argmax (first-max, matches jnp.argmax) ----------
    if (t >= 1 && t < TMAX && tid < ROWS) {
      float best = logits_lds[tid][0];
      int bi = 0;
      for (int x = 1; x < VOCAB; ++x) {
        float val = logits_lds[tid][x];
        if (val > best) { best = val; bi = x; }
      }
      pred_lds[tid] = bi;
    }
    __syncthreads();

    // ---------- gate nonlinearity + h update (no gh LDS round-trip) ----------
    if (is_gate && t < TMAX) {
      #pragma unroll
      for (int r = 0; r < ROWS; ++r) {
        const float* eb = EIH + (size_t)pred_lds[r] * G3;
        float gir = eb[u], giz = eb[HID + u], gin = eb[2 * HID + u];
        float rg = 1.f / (1.f + expf(-(gir + accr[r])));
        float zg = 1.f / (1.f + expf(-(giz + accz[r])));
        float ng = tanhf(gin + rg * accn[r]);
        h_lds[r][u] = (1.f - zg) * ng + zg * h_lds[r][u];
      }
    }
    __syncthreads();
  }
}

extern "C" void kernel_launch(void* const* d_in, const int* in_sizes, int n_in,
                              void* d_out, int out_size, void* d_ws, size_t ws_size,
                              hipStream_t stream)
{
  const float* feat   = (const float*)d_in[0];
  const float* W_ih   = (const float*)d_in[1];
  const float* W_hh   = (const float*)d_in[2];
  const float* b_ih   = (const float*)d_in[3];
  const float* b_hh   = (const float*)d_in[4];
  const float* W_proj = (const float*)d_in[5];
  const float* b_proj = (const float*)d_in[6];
  const float* embed  = (const float*)d_in[7];
  const int*   sos    = (const int*)d_in[8];
  float* ws  = (float*)d_ws;
  float* out = (float*)d_out;

  const int total = SZ_GTI + SZ_WIHT + SZ_BEXT;
  prep_kernel<<<(total + 255) / 256, 256, 0, stream>>>(W_ih, W_hh, b_hh, W_proj, b_proj, ws);
  eih_kernel<<<600, 256, 0, stream>>>(embed, b_ih, ws);
  decode_kernel<<<NWG, BLOCK, 0, stream>>>(feat, sos, ws, out);
}

// Round 4
// 12844.969 us; speedup vs baseline: 1.0068x; 1.0055x over previous
//
#include <hip/hip_runtime.h>
#include <cmath>

#define HID   512
#define VOCAB 100
#define G3    1536          // 3*HID
#define GEXT  1664          // G3 + 100 logits + pad
#define TMAX  201
#define ROWS  8
#define BLOCK 640
#define NWG   256

// ---- workspace layout (float offsets) ----
#define SZ_GTI   (HID * GEXT)          // 851968: interleaved [kc][j][kk4]
#define OFF_GTI  0
#define SZ_EIH   (VOCAB * G3)          // 153600: E_ih = embed @ W_ih^T + b_ih
#define OFF_EIH  (OFF_GTI + SZ_GTI)
#define SZ_WIHT  (HID * G3)            // 786432: W_ih transposed [k][j]
#define OFF_WIHT (OFF_EIH + SZ_EIH)
#define SZ_BEXT  GEXT                  // 1664: [b_hh | b_proj | 0-pad]
#define OFF_BEXT (OFF_WIHT + SZ_WIHT)
// total = 1,793,664 floats = ~7.2 MB of d_ws

// Build GTI (k4-interleaved extended weight matrix), W_ihT, bias_ext.
// GTI float index = (kc*GEXT + j)*4 + kk, where k = kc*4+kk.
// Columns j: [0,1536) = W_hh rows (r,z,n gates); [1536,1636) = W_proj rows; pad=0.
__global__ void prep_kernel(const float* __restrict__ W_ih,
                            const float* __restrict__ W_hh,
                            const float* __restrict__ b_hh,
                            const float* __restrict__ W_proj,
                            const float* __restrict__ b_proj,
                            float* __restrict__ ws)
{
  int idx = blockIdx.x * blockDim.x + threadIdx.x;
  const int total = SZ_GTI + SZ_WIHT + SZ_BEXT;
  if (idx >= total) return;
  if (idx < SZ_GTI) {
    int kc  = idx / (GEXT * 4);
    int rem = idx - kc * (GEXT * 4);
    int j   = rem >> 2;
    int kk  = rem & 3;
    int k   = kc * 4 + kk;
    float val = 0.f;
    if (j < G3)              val = W_hh[j * HID + k];
    else if (j < G3 + VOCAB) val = W_proj[(j - G3) * HID + k];
    ws[OFF_GTI + idx] = val;
  } else if (idx < SZ_GTI + SZ_WIHT) {
    int e = idx - SZ_GTI;
    int k = e / G3;
    int j = e - k * G3;
    ws[OFF_WIHT + e] = W_ih[j * HID + k];
  } else {
    int j = idx - SZ_GTI - SZ_WIHT;
    float val = 0.f;
    if (j < G3)              val = b_hh[j];
    else if (j < G3 + VOCAB) val = b_proj[j - G3];
    ws[OFF_BEXT + j] = val;
  }
}

// E_ih[v][j] = b_ih[j] + sum_k embed[v][k] * W_ih[j][k]   (coalesced via W_ihT)
__global__ void eih_kernel(const float* __restrict__ embed,
                           const float* __restrict__ b_ih,
                           float* __restrict__ ws)
{
  int v = blockIdx.x / 6;
  int j = (blockIdx.x % 6) * 256 + threadIdx.x;
  const float* WihT = ws + OFF_WIHT;
  const float* e = embed + v * HID;
  float acc = b_ih[j];
  for (int k = 0; k < HID; ++k)
    acc = fmaf(WihT[k * G3 + j], e[k], acc);
  ws[OFF_EIH + v * G3 + j] = acc;
}

// Persistent per-block GRU decode: 8 batch rows per block, 202 iterations.
// Iteration t: extended GEMV on h(=H_t) gives gh_t (cols 0..1535) and
// logits_{t-1} (cols 1536..1635); argmax -> pred_{t-1}; gate math -> H_{t+1}.
__global__ __launch_bounds__(BLOCK) void decode_kernel(
    const float* __restrict__ feat,
    const int* __restrict__ sos,
    const float* __restrict__ ws,
    float* __restrict__ out)
{
  __shared__ float h_lds[ROWS][HID];
  __shared__ float logits_lds[ROWS][132];   // stride 132 breaks argmax bank aliasing
  __shared__ int   pred_lds[ROWS];

  const float* __restrict__ GTI  = ws + OFF_GTI;
  const float* __restrict__ EIH  = ws + OFF_EIH;
  const float* __restrict__ bext = ws + OFF_BEXT;

  const int tid = threadIdx.x;
  const int b0  = blockIdx.x * ROWS;

  for (int i = tid; i < ROWS * HID; i += BLOCK) {
    int r = i >> 9, k = i & (HID - 1);
    h_lds[r][k] = feat[(b0 + r) * HID + k];
  }
  if (tid < ROWS) pred_lds[tid] = sos[0];
  __syncthreads();

  const bool is_gate = (tid < HID);   // threads [0,512): own unit u = tid (r,z,n triplet)
  const int  u = tid;
  const int  v = tid - HID;           // threads [512,640): logit column v in [0,128)

  float bias0 = 0.f, bias1 = 0.f, bias2 = 0.f;
  if (is_gate) { bias0 = bext[u]; bias1 = bext[HID + u]; bias2 = bext[2 * HID + u]; }
  else         { bias0 = bext[G3 + v]; }

  float accr[ROWS], accz[ROWS], accn[ROWS];

  for (int t = 0; t <= TMAX; ++t) {
    // ---------- phase A: extended GEMV over k ----------
    if (is_gate) {
      #pragma unroll
      for (int r = 0; r < ROWS; ++r) { accr[r] = bias0; accz[r] = bias1; accn[r] = bias2; }
      if (t < TMAX) {  // last iteration needs only logits
        const float4* pr = (const float4*)GTI + u;
        const float4* pz = (const float4*)GTI + HID + u;
        const float4* pn = (const float4*)GTI + 2 * HID + u;
        for (int kc = 0; kc < HID / 4; ++kc) {
          float4 wr = pr[kc * GEXT];
          float4 wz = pz[kc * GEXT];
          float4 wn = pn[kc * GEXT];
          #pragma unroll
          for (int r = 0; r < ROWS; ++r) {
            float4 hv = *(const float4*)&h_lds[r][kc * 4];   // LDS broadcast
            accr[r] = fmaf(wr.x, hv.x, accr[r]); accr[r] = fmaf(wr.y, hv.y, accr[r]);
            accr[r] = fmaf(wr.z, hv.z, accr[r]); accr[r] = fmaf(wr.w, hv.w, accr[r]);
            accz[r] = fmaf(wz.x, hv.x, accz[r]); accz[r] = fmaf(wz.y, hv.y, accz[r]);
            accz[r] = fmaf(wz.z, hv.z, accz[r]); accz[r] = fmaf(wz.w, hv.w, accz[r]);
            accn[r] = fmaf(wn.x, hv.x, accn[r]); accn[r] = fmaf(wn.y, hv.y, accn[r]);
            accn[r] = fmaf(wn.z, hv.z, accn[r]); accn[r] = fmaf(wn.w, hv.w, accn[r]);
          }
        }
      }
    } else {
      #pragma unroll
      for (int r = 0; r < ROWS; ++r) accr[r] = bias0;
      const float4* pv = (const float4*)GTI + G3 + v;
      for (int kc = 0; kc < HID / 4; ++kc) {
        float4 wv = pv[kc * GEXT];
        #pragma unroll
        for (int r = 0; r < ROWS; ++r) {
          float4 hv = *(const float4*)&h_lds[r][kc * 4];
          accr[r] = fmaf(wv.x, hv.x, accr[r]); accr[r] = fmaf(wv.y, hv.y, accr[r]);
          accr[r] = fmaf(wv.z, hv.z, accr[r]); accr[r] = fmaf(wv.w, hv.w, accr[r]);
        }
      }
      #pragma unroll
      for (int r = 0; r < ROWS; ++r) logits_lds[r][v] = accr[r];
      if (t >= 1 && v < VOCAB) {   // logits_{t-1} -> out[b][v][t-1]
        #pragma unroll
        for (int r = 0; r < ROWS; ++r)
          __builtin_nontemporal_store(
              accr[r], &out[((size_t)(b0 + r) * VOCAB + v) * TMAX + (t - 1)]);
      }
    }
    __syncthreads();

    // ---------- argmax (first-max, matches jnp.argmax) ----------
    if (t >= 1 && t < TMAX && tid < ROWS) {
      float best = logits_lds[tid][0];
      int bi = 0;
      for (int x = 1; x < VOCAB; ++x) {
        float val = logits_lds[tid][x];
        if (val > best) { best = val; bi = x; }
      }
      pred_lds[tid] = bi;
    }
    __syncthreads();

    // ---------- gate nonlinearity + h update (no gh LDS round-trip) ----------
    if (is_gate && t < TMAX) {
      #pragma unroll
      for (int r = 0; r < ROWS; ++r) {
        const float* eb = EIH + (size_t)pred_lds[r] * G3;
        float gir = eb[u], giz = eb[HID + u], gin = eb[2 * HID + u];
        float rg = 1.f / (1.f + expf(-(gir + accr[r])));
        float zg = 1.f / (1.f + expf(-(giz + accz[r])));
        float ng = tanhf(gin + rg * accn[r]);
        h_lds[r][u] = (1.f - zg) * ng + zg * h_lds[r][u];
      }
    }
    __syncthreads();
  }
}

extern "C" void kernel_launch(void* const* d_in, const int* in_sizes, int n_in,
                              void* d_out, int out_size, void* d_ws, size_t ws_size,
                              hipStream_t stream)
{
  const float* feat   = (const float*)d_in[0];
  const float* W_ih   = (const float*)d_in[1];
  const float* W_hh   = (const float*)d_in[2];
  const float* b_ih   = (const float*)d_in[3];
  const float* b_hh   = (const float*)d_in[4];
  const float* W_proj = (const float*)d_in[5];
  const float* b_proj = (const float*)d_in[6];
  const float* embed  = (const float*)d_in[7];
  const int*   sos    = (const int*)d_in[8];
  float* ws  = (float*)d_ws;
  float* out = (float*)d_out;

  const int total = SZ_GTI + SZ_WIHT + SZ_BEXT;
  prep_kernel<<<(total + 255) / 256, 256, 0, stream>>>(W_ih, W_hh, b_hh, W_proj, b_proj, ws);
  eih_kernel<<<600, 256, 0, stream>>>(embed, b_ih, ws);
  decode_kernel<<<NWG, BLOCK, 0, stream>>>(feat, sos, ws, out);
}

// Round 5
// 7293.892 us; speedup vs baseline: 1.7730x; 1.7611x over previous
//
#include <hip/hip_runtime.h>
#include <cmath>

#define HID   512
#define VOCAB 100
#define G3    1536            // 3*HID
#define GEXT  1664            // G3 + 100 logits + 28 pad (104 tiles of 16)
#define NT    104             // column tiles of 16
#define TMAX  201
#define ROWS  8
#define BLOCK 512             // 8 waves
#define NWG   256
#define TPW   13              // tiles per wave (104/8)

typedef __bf16 bf16x8 __attribute__((ext_vector_type(8)));
typedef float  f32x4  __attribute__((ext_vector_type(4)));

// ---- workspace layout ----
// WPK (bf16): packed MFMA B-fragments, [tile][kstep][half(hi/lo)][lane][8]
#define SZ_WPK   (NT * 16 * 2 * 64 * 8)   // 1,703,936 bf16 = 3.4 MB
#define FBASE    (SZ_WPK / 2)             // float-index base after WPK
#define OFF_EIH  FBASE                    // E_ih = embed @ W_ih^T + b_ih   [100][1536] f32
#define SZ_EIH   (VOCAB * G3)
#define OFF_WIHT (OFF_EIH + SZ_EIH)       // W_ih transposed [k][j] f32
#define SZ_WIHT  (HID * G3)
#define OFF_BEXT (OFF_WIHT + SZ_WIHT)     // [b_hh | b_proj | 0-pad]  [1664] f32
// total = 3,407,872 + 4*941,696 = 7,174,656 bytes

// Build W_ihT and bias_ext.
__global__ void prep_kernel(const float* __restrict__ W_ih,
                            const float* __restrict__ b_hh,
                            const float* __restrict__ b_proj,
                            float* __restrict__ ws)
{
  int idx = blockIdx.x * 256 + threadIdx.x;
  if (idx < SZ_WIHT) {
    int k = idx / G3, j = idx - k * G3;
    ws[OFF_WIHT + idx] = W_ih[j * HID + k];
  } else if (idx < SZ_WIHT + GEXT) {
    int j = idx - SZ_WIHT;
    float v = 0.f;
    if (j < G3)              v = b_hh[j];
    else if (j < G3 + VOCAB) v = b_proj[j - G3];
    ws[OFF_BEXT + j] = v;
  }
}

// Pack W (= [W_hh rows | W_proj rows | 0]) into split-bf16 MFMA B-fragments.
// B-frag layout for mfma_f32_16x16x32_bf16: lane l holds B[k=(l>>4)*8+j][col=l&15].
__global__ void pack_kernel(const float* __restrict__ W_hh,
                            const float* __restrict__ W_proj,
                            __bf16* __restrict__ wpk)
{
  int idx = blockIdx.x * 256 + threadIdx.x;      // element (c,ks,lane,j)
  if (idx >= NT * 16 * 64 * 8) return;
  int j    = idx & 7;
  int lane = (idx >> 3) & 63;
  int ks   = (idx >> 9) & 15;
  int c    = idx >> 13;
  int col  = c * 16 + (lane & 15);
  int k    = ks * 32 + (lane >> 4) * 8 + j;
  float w = 0.f;
  if (col < G3)              w = W_hh[col * HID + k];
  else if (col < G3 + VOCAB) w = W_proj[(col - G3) * HID + k];
  __bf16 hi = (__bf16)w;
  __bf16 lo = (__bf16)(w - (float)hi);
  int base = (((c * 16 + ks) * 2) * 64 + lane) * 8 + j;
  wpk[base]       = hi;
  wpk[base + 512] = lo;                          // lo-half is +64*8 elements
}

// E_ih[v][j] = b_ih[j] + sum_k embed[v][k] * W_ih[j][k]
__global__ void eih_kernel(const float* __restrict__ embed,
                           const float* __restrict__ b_ih,
                           float* __restrict__ ws)
{
  int v = blockIdx.x / 6;
  int j = (blockIdx.x % 6) * 256 + threadIdx.x;
  const float* WihT = ws + OFF_WIHT;
  const float* e = embed + v * HID;
  float acc = b_ih[j];
  for (int k = 0; k < HID; ++k)
    acc = fmaf(WihT[k * G3 + j], e[k], acc);
  ws[OFF_EIH + v * G3 + j] = acc;
}

// Persistent GRU decode, 8 rows/block, MFMA split-bf16.
// A-tile = [H_hi(8 rows); H_lo(8 rows)]; both W_hi and W_lo passes accumulate
// into one acc; final acc[r]+acc[r+8] = full fp32-accurate H @ W.
__global__ __launch_bounds__(BLOCK, 2) void decode_kernel(
    const float* __restrict__ feat,
    const int* __restrict__ sos,
    const float* __restrict__ ws,
    const __bf16* __restrict__ wpk,
    float* __restrict__ out)
{
  __shared__ __align__(16) char hab[16 * 1024];      // ha[16 rows][512] bf16, XOR-swizzled
  __shared__ float gh[ROWS][GEXT + 1];               // +1 pad: argmax bank spread
  __shared__ int   pred_lds[ROWS];

  const float* __restrict__ EIH  = ws + OFF_EIH;
  const float* __restrict__ bext = ws + OFF_BEXT;

  const int tid  = threadIdx.x;
  const int lane = tid & 63;
  const int wv   = tid >> 6;
  const int b0   = blockIdx.x * ROWS;

  // ---- init: h in regs (unit u = tid, 8 rows), write split-bf16 to ha ----
  float h[ROWS];
  #pragma unroll
  for (int r = 0; r < ROWS; ++r) {
    float f = feat[(size_t)(b0 + r) * HID + tid];
    h[r] = f;
    __bf16 hi = (__bf16)f;
    __bf16 lo = (__bf16)(f - (float)hi);
    unsigned so = ((unsigned)(tid * 2)) ^ (((unsigned)(r & 7)) << 4);
    *(__bf16*)(hab + (r << 10) + so)       = hi;
    *(__bf16*)(hab + ((r + 8) << 10) + so) = lo;
  }
  if (tid < ROWS) pred_lds[tid] = sos[0];
  __syncthreads();

  // A-frag addressing: lane l reads A[row=l&15][k=(l>>4)*8+j]
  const int      arow  = lane & 15;
  const unsigned abase = (unsigned)(arow << 10);
  const unsigned axor  = ((unsigned)(arow & 7)) << 4;
  const unsigned ag    = (unsigned)((lane >> 4) << 4);

  for (int t = 0; t <= TMAX; ++t) {
    // ---------- load A-frags (16 k-steps) from ha ----------
    bf16x8 afr[16];
    #pragma unroll
    for (int ks = 0; ks < 16; ++ks)
      afr[ks] = *(const bf16x8*)(hab + abase + ((((unsigned)ks << 6) + ag) ^ axor));

    // ---------- MFMA: 13 col-tiles, 2 passes (W_hi, W_lo) fused ----------
    for (int tt = 0; tt < TPW; ++tt) {
      int tile = wv * TPW + tt;
      f32x4 acc = {0.f, 0.f, 0.f, 0.f};
      const bf16x8* bp = ((const bf16x8*)wpk) + ((size_t)tile * 32 * 64 + lane);
      #pragma unroll
      for (int ks = 0; ks < 16; ++ks) {
        bf16x8 bh = bp[ks * 128];
        bf16x8 bl = bp[ks * 128 + 64];
        acc = __builtin_amdgcn_mfma_f32_16x16x32_bf16(afr[ks], bh, acc, 0, 0, 0);
        acc = __builtin_amdgcn_mfma_f32_16x16x32_bf16(afr[ks], bl, acc, 0, 0, 0);
      }
      // combine: rows 8-15 (lanes 32-63) hold the lo-row terms; add to rows 0-7
      int colw = tile * 16 + (lane & 15);
      float bias = bext[colw];
      float vsum[4];
      #pragma unroll
      for (int i = 0; i < 4; ++i)
        vsum[i] = acc[i] + __shfl_xor(acc[i], 32, 64);
      if (lane < 32) {
        int rbase = (lane >> 4) * 4;
        #pragma unroll
        for (int i = 0; i < 4; ++i)
          gh[rbase + i][colw] = vsum[i] + bias;
      }
    }
    __syncthreads();   // gh (gates + logits) ready

    // ---------- logits out + argmax (logits_{t-1} live in gh cols 1536+) ----------
    if (t >= 1) {
      if (tid < VOCAB) {
        #pragma unroll
        for (int r = 0; r < ROWS; ++r)
          __builtin_nontemporal_store(
              gh[r][G3 + tid],
              &out[((size_t)(b0 + r) * VOCAB + tid) * TMAX + (t - 1)]);
      }
      if (t < TMAX && tid < ROWS) {
        float best = gh[tid][G3];
        int bi = 0;
        for (int x = 1; x < VOCAB; ++x) {
          float val = gh[tid][G3 + x];
          if (val > best) { best = val; bi = x; }
        }
        pred_lds[tid] = bi;
      }
    }
    __syncthreads();   // pred ready

    // ---------- gate nonlinearity + h update + split-bf16 writeback ----------
    if (t < TMAX) {
      const int u = tid;
      #pragma unroll
      for (int r = 0; r < ROWS; ++r) {
        const float* eb = EIH + (size_t)pred_lds[r] * G3;
        float rg = 1.f / (1.f + expf(-(eb[u]           + gh[r][u])));
        float zg = 1.f / (1.f + expf(-(eb[HID + u]     + gh[r][HID + u])));
        float ng = tanhf(eb[2 * HID + u] + rg * gh[r][2 * HID + u]);
        h[r] = (1.f - zg) * ng + zg * h[r];
        __bf16 hi = (__bf16)h[r];
        __bf16 lo = (__bf16)(h[r] - (float)hi);
        unsigned so = ((unsigned)(u * 2)) ^ (((unsigned)(r & 7)) << 4);
        *(__bf16*)(hab + (r << 10) + so)       = hi;
        *(__bf16*)(hab + ((r + 8) << 10) + so) = lo;
      }
    }
    __syncthreads();   // ha ready for next step; gh free to overwrite
  }
}

extern "C" void kernel_launch(void* const* d_in, const int* in_sizes, int n_in,
                              void* d_out, int out_size, void* d_ws, size_t ws_size,
                              hipStream_t stream)
{
  const float* feat   = (const float*)d_in[0];
  const float* W_ih   = (const float*)d_in[1];
  const float* W_hh   = (const float*)d_in[2];
  const float* b_ih   = (const float*)d_in[3];
  const float* b_hh   = (const float*)d_in[4];
  const float* W_proj = (const float*)d_in[5];
  const float* b_proj = (const float*)d_in[6];
  const float* embed  = (const float*)d_in[7];
  const int*   sos    = (const int*)d_in[8];

  float*  wsf = (float*)d_ws;
  __bf16* wpk = (__bf16*)d_ws;
  float*  out = (float*)d_out;

  const int prep_total = SZ_WIHT + GEXT;
  prep_kernel<<<(prep_total + 255) / 256, 256, 0, stream>>>(W_ih, b_hh, b_proj, wsf);
  pack_kernel<<<(NT * 16 * 64 * 8 + 255) / 256, 256, 0, stream>>>(W_hh, W_proj, wpk);
  eih_kernel<<<600, 256, 0, stream>>>(embed, b_ih, wsf);
  decode_kernel<<<NWG, BLOCK, 0, stream>>>(feat, sos, wsf, wpk, out);
}